// Round 12
// baseline (324.888 us; speedup 1.0000x reference)
//
#include <hip/hip_runtime.h>
#include <hip/hip_bf16.h>
#include <cmath>

#define NN 100000
#define IND 512
#define HID 64
#define NC  40
#define BWN 256                      // nodes per bucket
#define NBKT ((NN + BWN - 1) / BWN)  // 391
#define CAP  12288                   // padded slots per bucket (avg 8184, +50%)
#define NBIN_BLOCKS 200

typedef unsigned int uint32;
typedef unsigned short ushort;
using short8 = __attribute__((ext_vector_type(8))) short;
using f32x4  = __attribute__((ext_vector_type(4))) float;

__device__ inline float bf_lo(uint32 u) { return __uint_as_float(u << 16); }
__device__ inline float bf_hi(uint32 u) { return __uint_as_float(u & 0xFFFF0000u); }
__device__ inline uint32 f2bf(float f) {
    uint32 u = __float_as_uint(f);
    return (u + 0x7FFFu + ((u >> 16) & 1u)) >> 16;  // RNE
}
__device__ inline uint32 pack2bf(float a, float b) { return f2bf(a) | (f2bf(b) << 16); }

union bfpack { uint32 u[4]; short8 s; };

// ---------------- wt_init: W1T + W2T bf16 transposes + gcursor init ----------------

__global__ __launch_bounds__(256) void wt_init_kernel(const float* __restrict__ W1,
                                                      const float* __restrict__ W2,
                                                      ushort* __restrict__ w1t,
                                                      ushort* __restrict__ w2t,
                                                      int* __restrict__ gcursor) {
    int id = blockIdx.x * blockDim.x + threadIdx.x;
    if (id < IND * HID) {
        int n = id & 63, k = id >> 6;
        w1t[(size_t)n * IND + k] = (ushort)f2bf(W1[(size_t)k * HID + n]);
    } else if (id < IND * HID + 48 * HID) {
        int id2 = id - IND * HID;
        int n = id2 >> 6, k = id2 & 63;
        w2t[id2] = (n < NC) ? (ushort)f2bf(W2[(size_t)k * NC + n]) : (ushort)0;
    }
    if (id < NBKT) gcursor[id] = id * CAP;
}

// ---------------- bin: bucket edges into padded staging ----------------

__global__ __launch_bounds__(512) void bin_kernel(const int* __restrict__ src,
                                                  const int* __restrict__ dst,
                                                  int* __restrict__ gcursor,
                                                  int* __restrict__ packed, int E) {
    __shared__ int hist[NBKT], base[NBKT], cur[NBKT];
    int b = blockIdx.x, t = threadIdx.x;
    int epb = (E + gridDim.x - 1) / gridDim.x;
    int lo = b * epb;
    int hi = lo + epb; if (hi > E) hi = E;
    for (int i = t; i < NBKT; i += 512) { hist[i] = 0; cur[i] = 0; }
    __syncthreads();
    for (int e = lo + t; e < hi; e += 512) atomicAdd(&hist[dst[e] >> 8], 1);
    __syncthreads();
    for (int i = t; i < NBKT; i += 512)
        if (hist[i]) base[i] = atomicAdd(&gcursor[i], hist[i]);
    __syncthreads();
    for (int e = lo + t; e < hi; e += 512) {
        int d = dst[e], s = src[e];
        int bk = d >> 8;
        int pos = base[bk] + atomicAdd(&cur[bk], 1);
        packed[pos] = ((d & 255) << 17) | s;
    }
}

// ---------------- csr_bucket: per-bucket node sort -> padded CSR + dinv ----------------

__global__ __launch_bounds__(256) void csr_bucket_kernel(const int* __restrict__ packed,
                                                         const int* __restrict__ gcursor,
                                                         int* __restrict__ rowptr,
                                                         int* __restrict__ rowend,
                                                         int* __restrict__ colx,
                                                         float* __restrict__ dinv) {
    __shared__ int hist[BWN], pfx[BWN], cur[BWN];
    int b = blockIdx.x, t = threadIdx.x;
    int nlo = b * BWN;
    int ncnt = NN - nlo; if (ncnt > BWN) ncnt = BWN;
    int ebeg = b * CAP, eend = gcursor[b];
    hist[t] = 0;
    __syncthreads();
    for (int e = ebeg + t; e < eend; e += 256) atomicAdd(&hist[packed[e] >> 17], 1);
    __syncthreads();
    int h = hist[t];
    pfx[t] = h;
    __syncthreads();
    for (int off = 1; off < 256; off <<= 1) {
        int u = (t >= off) ? pfx[t - off] : 0;
        __syncthreads();
        pfx[t] += u;
        __syncthreads();
    }
    int excl = pfx[t] - h;
    cur[t] = excl;
    int g = nlo + t;
    if (t < ncnt) {
        rowptr[g] = ebeg + excl;
        rowend[g] = ebeg + excl + h;
        dinv[g] = rsqrtf((float)(h + 1));  // +1 self-loop
    }
    __syncthreads();
    for (int e = ebeg + t; e < eend; e += 256) {
        int p = packed[e];
        int dl = p >> 17;
        int s = p & 0x1FFFF;
        int pos = ebeg + atomicAdd(&cur[dl], 1);
        colx[pos] = s;
    }
}

// ---------------- Layer 1 GEMM (MFMA bf16, LDS-free) ----------------
// Each wave owns 16 rows; A fragments loaded directly from x (coalesced:
// lanes r,r+16,r+32,r+48 cover row r's 128B f32 k-chunk), converted to bf16
// in-register; B fragments straight from L2-hot w1t. No LDS, no barriers.

__global__ __launch_bounds__(256) void gemm1_mfma(const float* __restrict__ x,
                                                  const ushort* __restrict__ w1t,
                                                  const float* __restrict__ dinv,
                                                  ushort* __restrict__ hs, int M) {
    int t = threadIdx.x;
    int w = t >> 6, l = t & 63;
    int lr = l & 15, lh = l >> 4;
    int row0 = blockIdx.x * 64 + w * 16;
    int arow = row0 + lr; if (arow > M - 1) arow = M - 1;
    const float* xrow = x + (size_t)arow * IND;

    f32x4 acc[4] = {};

#pragma unroll 2
    for (int k0 = 0; k0 < IND; k0 += 32) {
        float4 p0 = *(const float4*)(xrow + k0 + lh * 8);
        float4 p1 = *(const float4*)(xrow + k0 + lh * 8 + 4);
        bfpack ap;
        ap.u[0] = pack2bf(p0.x, p0.y);
        ap.u[1] = pack2bf(p0.z, p0.w);
        ap.u[2] = pack2bf(p1.x, p1.y);
        ap.u[3] = pack2bf(p1.z, p1.w);
#pragma unroll
        for (int ns = 0; ns < 4; ++ns) {
            short8 b = *(const short8*)(w1t + (size_t)(ns * 16 + lr) * IND + k0 + lh * 8);
            acc[ns] = __builtin_amdgcn_mfma_f32_16x16x32_bf16(ap.s, b, acc[ns], 0, 0, 0);
        }
    }

    int rbase = row0 + lh * 4;
    float dv[4];
#pragma unroll
    for (int j = 0; j < 4; ++j) dv[j] = (rbase + j < M) ? dinv[rbase + j] : 0.f;
#pragma unroll
    for (int ns = 0; ns < 4; ++ns) {
        int col = ns * 16 + lr;
#pragma unroll
        for (int j = 0; j < 4; ++j) {
            int row = rbase + j;
            if (row < M) hs[(size_t)row * HID + col] = (ushort)f2bf(acc[ns][j] * dv[j]);
        }
    }
}

// ---------------- agg1: half-wave per node, bf16 gather, bf16 h1 out ----------------

__global__ __launch_bounds__(256) void agg1_kernel(const uint32* __restrict__ hs,
                                                   const int* __restrict__ rowptr,
                                                   const int* __restrict__ rowend,
                                                   const int* __restrict__ colx,
                                                   const float* __restrict__ dinv,
                                                   const float* __restrict__ b1,
                                                   uint32* __restrict__ h1) {
    int node = (blockIdx.x * blockDim.x + threadIdx.x) >> 5;
    int l = threadIdx.x & 31;
    if (node >= NN) return;
    int beg = rowptr[node], end = rowend[node];
    uint32 u = hs[(size_t)node * 32 + l];  // self (already dinv-scaled)
    float a0 = bf_lo(u), a1 = bf_hi(u);
    int e = beg;
    int n8 = beg + ((end - beg) & ~7);
    for (; e < n8; e += 8) {
        int c[8];
#pragma unroll
        for (int j = 0; j < 8; ++j) c[j] = __builtin_nontemporal_load(&colx[e + j]);
        uint32 uu[8];
#pragma unroll
        for (int j = 0; j < 8; ++j) uu[j] = hs[(size_t)c[j] * 32 + l];
#pragma unroll
        for (int j = 0; j < 8; ++j) { a0 += bf_lo(uu[j]); a1 += bf_hi(uu[j]); }
    }
    for (; e < end; ++e) {
        uint32 ue = hs[(size_t)__builtin_nontemporal_load(&colx[e]) * 32 + l];
        a0 += bf_lo(ue); a1 += bf_hi(ue);
    }
    float d = dinv[node];
    float2 bb = *(const float2*)(b1 + 2 * l);
    float v0 = a0 * d + bb.x;
    float v1 = a1 * d + bb.y;
    v0 = v0 > 0.f ? v0 : 0.f;
    v1 = v1 > 0.f ? v1 : 0.f;
    __builtin_nontemporal_store(pack2bf(v0, v1), &h1[(size_t)node * 32 + l]);
}

// ---------------- Layer 2 GEMM (MFMA, LDS-free): h2b = bf16((h1 @ W2) * dinv) ----------------

__global__ __launch_bounds__(256) void gemm2_mfma(const ushort* __restrict__ h1,
                                                  const ushort* __restrict__ w2t,
                                                  const float* __restrict__ dinv,
                                                  ushort* __restrict__ h2b, int M) {
    int t = threadIdx.x;
    int w = t >> 6, l = t & 63;
    int lr = l & 15, lh = l >> 4;
    int row0 = blockIdx.x * 64 + w * 16;
    int arow = row0 + lr; if (arow > M - 1) arow = M - 1;
    const ushort* hrow = h1 + (size_t)arow * HID;

    f32x4 acc[3] = {};
#pragma unroll
    for (int ks = 0; ks < 2; ++ks) {
        short8 a = *(const short8*)(hrow + ks * 32 + lh * 8);
#pragma unroll
        for (int ns = 0; ns < 3; ++ns) {
            short8 b = *(const short8*)(w2t + (size_t)(ns * 16 + lr) * HID + ks * 32 + lh * 8);
            acc[ns] = __builtin_amdgcn_mfma_f32_16x16x32_bf16(a, b, acc[ns], 0, 0, 0);
        }
    }

    int rbase = row0 + lh * 4;
    float dv[4];
#pragma unroll
    for (int j = 0; j < 4; ++j) dv[j] = (rbase + j < M) ? dinv[rbase + j] : 0.f;
#pragma unroll
    for (int ns = 0; ns < 3; ++ns) {
        int col = ns * 16 + lr;
        if (col < NC) {
#pragma unroll
            for (int j = 0; j < 4; ++j) {
                int row = rbase + j;
                if (row < M) h2b[(size_t)row * NC + col] = (ushort)f2bf(acc[ns][j] * dv[j]);
            }
        }
    }
}

// ---------------- agg2 + bias + log_softmax: half-wave per node ----------------

__global__ __launch_bounds__(256) void agg2_kernel(const uint32* __restrict__ h2b,
                                                   const int* __restrict__ rowptr,
                                                   const int* __restrict__ rowend,
                                                   const int* __restrict__ colx,
                                                   const float* __restrict__ dinv,
                                                   const float* __restrict__ b2,
                                                   float* __restrict__ out) {
    int node = (blockIdx.x * blockDim.x + threadIdx.x) >> 5;
    int l = threadIdx.x & 31;
    if (node >= NN) return;
    bool act = l < 20;
    int beg = rowptr[node], end = rowend[node];
    float a0 = 0.f, a1 = 0.f;
    if (act) {
        uint32 u = h2b[(size_t)node * 20 + l];
        a0 = bf_lo(u); a1 = bf_hi(u);
    }
    int e = beg;
    int n8 = beg + ((end - beg) & ~7);
    for (; e < n8; e += 8) {
        int c[8];
#pragma unroll
        for (int j = 0; j < 8; ++j) c[j] = __builtin_nontemporal_load(&colx[e + j]);
        if (act) {
            uint32 uu[8];
#pragma unroll
            for (int j = 0; j < 8; ++j) uu[j] = h2b[(size_t)c[j] * 20 + l];
#pragma unroll
            for (int j = 0; j < 8; ++j) { a0 += bf_lo(uu[j]); a1 += bf_hi(uu[j]); }
        }
    }
    for (; e < end; ++e) {
        int c = __builtin_nontemporal_load(&colx[e]);
        if (act) {
            uint32 ue = h2b[(size_t)c * 20 + l];
            a0 += bf_lo(ue); a1 += bf_hi(ue);
        }
    }

    float d = dinv[node];
    float v0 = -INFINITY, v1 = -INFINITY;
    if (act) {
        float2 bb = *(const float2*)(b2 + 2 * l);
        v0 = a0 * d + bb.x;
        v1 = a1 * d + bb.y;
    }
    float m = fmaxf(v0, v1);
#pragma unroll
    for (int off = 16; off; off >>= 1) m = fmaxf(m, __shfl_xor(m, off));
    float s = act ? (expf(v0 - m) + expf(v1 - m)) : 0.f;
#pragma unroll
    for (int off = 16; off; off >>= 1) s += __shfl_xor(s, off);
    if (act) {
        float ls = logf(s);
        __builtin_nontemporal_store(v0 - m - ls, &out[(size_t)node * NC + 2 * l]);
        __builtin_nontemporal_store(v1 - m - ls, &out[(size_t)node * NC + 2 * l + 1]);
    }
}

// ---------------- launch ----------------

extern "C" void kernel_launch(void* const* d_in, const int* in_sizes, int n_in,
                              void* d_out, int out_size, void* d_ws, size_t ws_size,
                              hipStream_t stream) {
    const float* x  = (const float*)d_in[0];
    const int* ei   = (const int*)d_in[1];
    const float* W1 = (const float*)d_in[2];
    const float* b1 = (const float*)d_in[3];
    const float* W2 = (const float*)d_in[4];
    const float* b2 = (const float*)d_in[5];
    float* out = (float*)d_out;

    const int E = in_sizes[1] / 2;
    const int* src = ei;
    const int* dst = ei + E;

    char* p = (char*)d_ws;
    size_t off = 0;
    auto carve = [&](size_t bytes) {
        void* q = p + off;
        off = (off + bytes + 255) & ~(size_t)255;
        return q;
    };
    int* gcursor  = (int*)carve((size_t)NBKT * 4);
    int* rowptr   = (int*)carve((size_t)NN * 4);
    int* rowend   = (int*)carve((size_t)NN * 4);
    float* dinv   = (float*)carve((size_t)NN * 4);
    ushort* w1t   = (ushort*)carve((size_t)IND * HID * 2);      // bf16 W1^T [64][512]
    ushort* w2t   = (ushort*)carve((size_t)48 * HID * 2);       // bf16 W2^T [48][64], padded
    ushort* hs    = (ushort*)carve((size_t)NN * HID * 2);       // bf16 [NN][64]
    uint32* h1    = (uint32*)carve((size_t)NN * 32 * 4);        // bf16 pairs [NN][32]
    ushort* h2b   = (ushort*)carve((size_t)NN * NC * 2);        // bf16 [NN][40]
    int* colx     = (int*)carve((size_t)NBKT * CAP * 4);        // padded CSR cols
    int* packed   = (int*)carve((size_t)NBKT * CAP * 4);        // padded bin staging

    wt_init_kernel<<<(IND * HID + 48 * HID + 255) / 256, 256, 0, stream>>>(W1, W2, w1t, w2t, gcursor);
    bin_kernel<<<NBIN_BLOCKS, 512, 0, stream>>>(src, dst, gcursor, packed, E);
    csr_bucket_kernel<<<NBKT, 256, 0, stream>>>(packed, gcursor, rowptr, rowend, colx, dinv);
    gemm1_mfma<<<(NN + 63) / 64, 256, 0, stream>>>(x, w1t, dinv, hs, NN);
    agg1_kernel<<<(NN * 32 + 255) / 256, 256, 0, stream>>>((const uint32*)hs, rowptr, rowend, colx, dinv, b1, h1);
    gemm2_mfma<<<(NN + 63) / 64, 256, 0, stream>>>((const ushort*)h1, w2t, dinv, h2b, NN);
    agg2_kernel<<<(NN * 32 + 255) / 256, 256, 0, stream>>>((const uint32*)h2b, rowptr, rowend, colx, dinv, b2, out);
}

// Round 13
// 289.975 us; speedup vs baseline: 1.1204x; 1.1204x over previous
//
#include <hip/hip_runtime.h>
#include <hip/hip_bf16.h>
#include <cmath>

#define NN 100000
#define IND 512
#define HID 64
#define NC  40
#define BWN 256                      // nodes per bucket
#define NBKT ((NN + BWN - 1) / BWN)  // 391
#define CAP  12288                   // padded slots per bucket (avg 8184, +50%)
#define NBIN_BLOCKS 200

typedef unsigned int uint32;
typedef unsigned short ushort;
using short8 = __attribute__((ext_vector_type(8))) short;
using f32x4  = __attribute__((ext_vector_type(4))) float;

__device__ inline float bf_lo(uint32 u) { return __uint_as_float(u << 16); }
__device__ inline float bf_hi(uint32 u) { return __uint_as_float(u & 0xFFFF0000u); }
__device__ inline uint32 f2bf(float f) {
    uint32 u = __float_as_uint(f);
    return (u + 0x7FFFu + ((u >> 16) & 1u)) >> 16;  // RNE
}
__device__ inline uint32 pack2bf(float a, float b) { return f2bf(a) | (f2bf(b) << 16); }

// ---------------- wt_init: W1T + W2T bf16 transposes + gcursor init ----------------

__global__ __launch_bounds__(256) void wt_init_kernel(const float* __restrict__ W1,
                                                      const float* __restrict__ W2,
                                                      ushort* __restrict__ w1t,
                                                      ushort* __restrict__ w2t,
                                                      int* __restrict__ gcursor) {
    int id = blockIdx.x * blockDim.x + threadIdx.x;
    if (id < IND * HID) {
        int n = id & 63, k = id >> 6;
        w1t[(size_t)n * IND + k] = (ushort)f2bf(W1[(size_t)k * HID + n]);
    } else if (id < IND * HID + 48 * HID) {
        int id2 = id - IND * HID;
        int n = id2 >> 6, k = id2 & 63;
        w2t[id2] = (n < NC) ? (ushort)f2bf(W2[(size_t)k * NC + n]) : (ushort)0;
    }
    if (id < NBKT) gcursor[id] = id * CAP;
}

// ---------------- bin: bucket edges into padded staging ----------------

__global__ __launch_bounds__(512) void bin_kernel(const int* __restrict__ src,
                                                  const int* __restrict__ dst,
                                                  int* __restrict__ gcursor,
                                                  int* __restrict__ packed, int E) {
    __shared__ int hist[NBKT], base[NBKT], cur[NBKT];
    int b = blockIdx.x, t = threadIdx.x;
    int epb = (E + gridDim.x - 1) / gridDim.x;
    int lo = b * epb;
    int hi = lo + epb; if (hi > E) hi = E;
    for (int i = t; i < NBKT; i += 512) { hist[i] = 0; cur[i] = 0; }
    __syncthreads();
    for (int e = lo + t; e < hi; e += 512) atomicAdd(&hist[dst[e] >> 8], 1);
    __syncthreads();
    for (int i = t; i < NBKT; i += 512)
        if (hist[i]) base[i] = atomicAdd(&gcursor[i], hist[i]);
    __syncthreads();
    for (int e = lo + t; e < hi; e += 512) {
        int d = dst[e], s = src[e];
        int bk = d >> 8;
        int pos = base[bk] + atomicAdd(&cur[bk], 1);
        packed[pos] = ((d & 255) << 17) | s;
    }
}

// ---------------- csr_bucket: per-bucket node sort -> padded CSR + dinv ----------------

__global__ __launch_bounds__(256) void csr_bucket_kernel(const int* __restrict__ packed,
                                                         const int* __restrict__ gcursor,
                                                         int* __restrict__ rowptr,
                                                         int* __restrict__ rowend,
                                                         int* __restrict__ colx,
                                                         float* __restrict__ dinv) {
    __shared__ int hist[BWN], pfx[BWN], cur[BWN];
    int b = blockIdx.x, t = threadIdx.x;
    int nlo = b * BWN;
    int ncnt = NN - nlo; if (ncnt > BWN) ncnt = BWN;
    int ebeg = b * CAP, eend = gcursor[b];
    hist[t] = 0;
    __syncthreads();
    for (int e = ebeg + t; e < eend; e += 256) atomicAdd(&hist[packed[e] >> 17], 1);
    __syncthreads();
    int h = hist[t];
    pfx[t] = h;
    __syncthreads();
    for (int off = 1; off < 256; off <<= 1) {
        int u = (t >= off) ? pfx[t - off] : 0;
        __syncthreads();
        pfx[t] += u;
        __syncthreads();
    }
    int excl = pfx[t] - h;
    cur[t] = excl;
    int g = nlo + t;
    if (t < ncnt) {
        rowptr[g] = ebeg + excl;
        rowend[g] = ebeg + excl + h;
        dinv[g] = rsqrtf((float)(h + 1));  // +1 self-loop
    }
    __syncthreads();
    for (int e = ebeg + t; e < eend; e += 256) {
        int p = packed[e];
        int dl = p >> 17;
        int s = p & 0x1FFFF;
        int pos = ebeg + atomicAdd(&cur[dl], 1);
        colx[pos] = s;
    }
}

// ---------------- Layer 1 GEMM (MFMA bf16, LDS-staged, reg-prefetch) ----------------
// NOTE: LDS staging beats LDS-free here (R12: 325 vs 290 µs total) — direct
// fragment loads stride 2KB across lanes (16 segments/instr from HBM), while
// staging keeps the x read fully coalesced and prefetch hides it under MFMA.

__global__ __launch_bounds__(256) void gemm1_mfma(const float* __restrict__ x,
                                                  const ushort* __restrict__ w1t,
                                                  const float* __restrict__ dinv,
                                                  ushort* __restrict__ hs, int M) {
    __shared__ ushort As[64 * 64];
    __shared__ ushort Bs[64 * 64];
    char* Ab = (char*)As;
    char* Bb = (char*)Bs;

    int t = threadIdx.x;
    int row0 = blockIdx.x * 64;

    int srow = t >> 2;
    int klane = t & 3;
    int grow = row0 + srow; if (grow > M - 1) grow = M - 1;
    const float* xrow = x + (size_t)grow * IND;
    const char* wrow = (const char*)(w1t + (size_t)srow * IND);
    int swrow = srow * 128;
    int swx = (srow & 7) << 4;

    int l = t & 63;
    int w = t >> 6;
    int lr = l & 15;
    int lk = (l >> 4) * 16;
    int arow_b = (w * 16 + lr) * 128;
    int aswz = ((w * 16 + lr) & 7) << 4;

    f32x4 acc[4] = {};

    float4 rx[4]; uint2 rw[4];
#pragma unroll
    for (int i = 0; i < 4; ++i) {
        rx[i] = *(const float4*)(xrow + i * 16 + klane * 4);
        rw[i] = *(const uint2*)(wrow + i * 32 + klane * 8);
    }

    for (int k0 = 0; k0 < IND; k0 += 64) {
#pragma unroll
        for (int i = 0; i < 4; ++i) {
            int kb = i * 32 + klane * 8;
            uint2 pkd;
            pkd.x = pack2bf(rx[i].x, rx[i].y);
            pkd.y = pack2bf(rx[i].z, rx[i].w);
            *(uint2*)(Ab + swrow + (kb ^ swx)) = pkd;
            *(uint2*)(Bb + swrow + (kb ^ swx)) = rw[i];
        }
        __syncthreads();

        if (k0 + 64 < IND) {
#pragma unroll
            for (int i = 0; i < 4; ++i) {
                rx[i] = *(const float4*)(xrow + k0 + 64 + i * 16 + klane * 4);
                rw[i] = *(const uint2*)(wrow + (k0 + 64) * 2 + i * 32 + klane * 8);
            }
        }

        short8 a0 = *(const short8*)(Ab + arow_b + ((0 + lk) ^ aswz));
        short8 a1 = *(const short8*)(Ab + arow_b + ((64 + lk) ^ aswz));
#pragma unroll
        for (int ns = 0; ns < 4; ++ns) {
            int brow = ns * 16 + lr;
            int bswz = (brow & 7) << 4;
            short8 b0 = *(const short8*)(Bb + brow * 128 + ((0 + lk) ^ bswz));
            short8 b1 = *(const short8*)(Bb + brow * 128 + ((64 + lk) ^ bswz));
            acc[ns] = __builtin_amdgcn_mfma_f32_16x16x32_bf16(a0, b0, acc[ns], 0, 0, 0);
            acc[ns] = __builtin_amdgcn_mfma_f32_16x16x32_bf16(a1, b1, acc[ns], 0, 0, 0);
        }
        __syncthreads();
    }

    int rbase = row0 + w * 16 + (l >> 4) * 4;
    float dv[4];
#pragma unroll
    for (int j = 0; j < 4; ++j) dv[j] = (rbase + j < M) ? dinv[rbase + j] : 0.f;
#pragma unroll
    for (int ns = 0; ns < 4; ++ns) {
        int col = ns * 16 + lr;
#pragma unroll
        for (int j = 0; j < 4; ++j) {
            int row = rbase + j;
            if (row < M) hs[(size_t)row * HID + col] = (ushort)f2bf(acc[ns][j] * dv[j]);
        }
    }
}

// ---------------- agg1: half-wave per node, bf16 gather, bf16 h1 out ----------------

__global__ __launch_bounds__(256) void agg1_kernel(const uint32* __restrict__ hs,
                                                   const int* __restrict__ rowptr,
                                                   const int* __restrict__ rowend,
                                                   const int* __restrict__ colx,
                                                   const float* __restrict__ dinv,
                                                   const float* __restrict__ b1,
                                                   uint32* __restrict__ h1) {
    int node = (blockIdx.x * blockDim.x + threadIdx.x) >> 5;
    int l = threadIdx.x & 31;
    if (node >= NN) return;
    int beg = rowptr[node], end = rowend[node];
    uint32 u = hs[(size_t)node * 32 + l];  // self (already dinv-scaled)
    float a0 = bf_lo(u), a1 = bf_hi(u);
    int e = beg;
    int n8 = beg + ((end - beg) & ~7);
    for (; e < n8; e += 8) {
        int c[8];
#pragma unroll
        for (int j = 0; j < 8; ++j) c[j] = __builtin_nontemporal_load(&colx[e + j]);
        uint32 uu[8];
#pragma unroll
        for (int j = 0; j < 8; ++j) uu[j] = hs[(size_t)c[j] * 32 + l];
#pragma unroll
        for (int j = 0; j < 8; ++j) { a0 += bf_lo(uu[j]); a1 += bf_hi(uu[j]); }
    }
    for (; e < end; ++e) {
        uint32 ue = hs[(size_t)__builtin_nontemporal_load(&colx[e]) * 32 + l];
        a0 += bf_lo(ue); a1 += bf_hi(ue);
    }
    float d = dinv[node];
    float2 bb = *(const float2*)(b1 + 2 * l);
    float v0 = a0 * d + bb.x;
    float v1 = a1 * d + bb.y;
    v0 = v0 > 0.f ? v0 : 0.f;
    v1 = v1 > 0.f ? v1 : 0.f;
    __builtin_nontemporal_store(pack2bf(v0, v1), &h1[(size_t)node * 32 + l]);
}

// ---------------- Layer 2 GEMM (MFMA, LDS-free): h2b = bf16((h1 @ W2) * dinv) ----------------

__global__ __launch_bounds__(256) void gemm2_mfma(const ushort* __restrict__ h1,
                                                  const ushort* __restrict__ w2t,
                                                  const float* __restrict__ dinv,
                                                  ushort* __restrict__ h2b, int M) {
    int t = threadIdx.x;
    int w = t >> 6, l = t & 63;
    int lr = l & 15, lh = l >> 4;
    int row0 = blockIdx.x * 64 + w * 16;
    int arow = row0 + lr; if (arow > M - 1) arow = M - 1;
    const ushort* hrow = h1 + (size_t)arow * HID;

    f32x4 acc[3] = {};
#pragma unroll
    for (int ks = 0; ks < 2; ++ks) {
        short8 a = *(const short8*)(hrow + ks * 32 + lh * 8);
#pragma unroll
        for (int ns = 0; ns < 3; ++ns) {
            short8 b = *(const short8*)(w2t + (size_t)(ns * 16 + lr) * HID + ks * 32 + lh * 8);
            acc[ns] = __builtin_amdgcn_mfma_f32_16x16x32_bf16(a, b, acc[ns], 0, 0, 0);
        }
    }

    int rbase = row0 + lh * 4;
    float dv[4];
#pragma unroll
    for (int j = 0; j < 4; ++j) dv[j] = (rbase + j < M) ? dinv[rbase + j] : 0.f;
#pragma unroll
    for (int ns = 0; ns < 3; ++ns) {
        int col = ns * 16 + lr;
        if (col < NC) {
#pragma unroll
            for (int j = 0; j < 4; ++j) {
                int row = rbase + j;
                if (row < M) h2b[(size_t)row * NC + col] = (ushort)f2bf(acc[ns][j] * dv[j]);
            }
        }
    }
}

// ---------------- agg2 + bias + log_softmax: half-wave per node ----------------

__global__ __launch_bounds__(256) void agg2_kernel(const uint32* __restrict__ h2b,
                                                   const int* __restrict__ rowptr,
                                                   const int* __restrict__ rowend,
                                                   const int* __restrict__ colx,
                                                   const float* __restrict__ dinv,
                                                   const float* __restrict__ b2,
                                                   float* __restrict__ out) {
    int node = (blockIdx.x * blockDim.x + threadIdx.x) >> 5;
    int l = threadIdx.x & 31;
    if (node >= NN) return;
    bool act = l < 20;
    int beg = rowptr[node], end = rowend[node];
    float a0 = 0.f, a1 = 0.f;
    if (act) {
        uint32 u = h2b[(size_t)node * 20 + l];
        a0 = bf_lo(u); a1 = bf_hi(u);
    }
    int e = beg;
    int n8 = beg + ((end - beg) & ~7);
    for (; e < n8; e += 8) {
        int c[8];
#pragma unroll
        for (int j = 0; j < 8; ++j) c[j] = __builtin_nontemporal_load(&colx[e + j]);
        if (act) {
            uint32 uu[8];
#pragma unroll
            for (int j = 0; j < 8; ++j) uu[j] = h2b[(size_t)c[j] * 20 + l];
#pragma unroll
            for (int j = 0; j < 8; ++j) { a0 += bf_lo(uu[j]); a1 += bf_hi(uu[j]); }
        }
    }
    for (; e < end; ++e) {
        int c = __builtin_nontemporal_load(&colx[e]);
        if (act) {
            uint32 ue = h2b[(size_t)c * 20 + l];
            a0 += bf_lo(ue); a1 += bf_hi(ue);
        }
    }

    float d = dinv[node];
    float v0 = -INFINITY, v1 = -INFINITY;
    if (act) {
        float2 bb = *(const float2*)(b2 + 2 * l);
        v0 = a0 * d + bb.x;
        v1 = a1 * d + bb.y;
    }
    float m = fmaxf(v0, v1);
#pragma unroll
    for (int off = 16; off; off >>= 1) m = fmaxf(m, __shfl_xor(m, off));
    float s = act ? (expf(v0 - m) + expf(v1 - m)) : 0.f;
#pragma unroll
    for (int off = 16; off; off >>= 1) s += __shfl_xor(s, off);
    if (act) {
        float ls = logf(s);
        __builtin_nontemporal_store(v0 - m - ls, &out[(size_t)node * NC + 2 * l]);
        __builtin_nontemporal_store(v1 - m - ls, &out[(size_t)node * NC + 2 * l + 1]);
    }
}

// ---------------- launch ----------------

extern "C" void kernel_launch(void* const* d_in, const int* in_sizes, int n_in,
                              void* d_out, int out_size, void* d_ws, size_t ws_size,
                              hipStream_t stream) {
    const float* x  = (const float*)d_in[0];
    const int* ei   = (const int*)d_in[1];
    const float* W1 = (const float*)d_in[2];
    const float* b1 = (const float*)d_in[3];
    const float* W2 = (const float*)d_in[4];
    const float* b2 = (const float*)d_in[5];
    float* out = (float*)d_out;

    const int E = in_sizes[1] / 2;
    const int* src = ei;
    const int* dst = ei + E;

    char* p = (char*)d_ws;
    size_t off = 0;
    auto carve = [&](size_t bytes) {
        void* q = p + off;
        off = (off + bytes + 255) & ~(size_t)255;
        return q;
    };
    int* gcursor  = (int*)carve((size_t)NBKT * 4);
    int* rowptr   = (int*)carve((size_t)NN * 4);
    int* rowend   = (int*)carve((size_t)NN * 4);
    float* dinv   = (float*)carve((size_t)NN * 4);
    ushort* w1t   = (ushort*)carve((size_t)IND * HID * 2);      // bf16 W1^T [64][512]
    ushort* w2t   = (ushort*)carve((size_t)48 * HID * 2);       // bf16 W2^T [48][64], padded
    ushort* hs    = (ushort*)carve((size_t)NN * HID * 2);       // bf16 [NN][64]
    uint32* h1    = (uint32*)carve((size_t)NN * 32 * 4);        // bf16 pairs [NN][32]
    ushort* h2b   = (ushort*)carve((size_t)NN * NC * 2);        // bf16 [NN][40]
    int* colx     = (int*)carve((size_t)NBKT * CAP * 4);        // padded CSR cols
    int* packed   = (int*)carve((size_t)NBKT * CAP * 4);        // padded bin staging

    wt_init_kernel<<<(IND * HID + 48 * HID + 255) / 256, 256, 0, stream>>>(W1, W2, w1t, w2t, gcursor);
    bin_kernel<<<NBIN_BLOCKS, 512, 0, stream>>>(src, dst, gcursor, packed, E);
    csr_bucket_kernel<<<NBKT, 256, 0, stream>>>(packed, gcursor, rowptr, rowend, colx, dinv);
    gemm1_mfma<<<(NN + 63) / 64, 256, 0, stream>>>(x, w1t, dinv, hs, NN);
    agg1_kernel<<<(NN * 32 + 255) / 256, 256, 0, stream>>>((const uint32*)hs, rowptr, rowend, colx, dinv, b1, h1);
    gemm2_mfma<<<(NN + 63) / 64, 256, 0, stream>>>((const ushort*)h1, w2t, dinv, h2b, NN);
    agg2_kernel<<<(NN * 32 + 255) / 256, 256, 0, stream>>>((const uint32*)h2b, rowptr, rowend, colx, dinv, b2, out);
}

// Round 14
// 281.411 us; speedup vs baseline: 1.1545x; 1.0304x over previous
//
#include <hip/hip_runtime.h>
#include <hip/hip_bf16.h>
#include <hip/hip_fp8.h>
#include <cmath>

#define NN 100000
#define IND 512
#define HID 64
#define NC  40
#define BWN 256                      // nodes per bucket
#define NBKT ((NN + BWN - 1) / BWN)  // 391
#define CAP  12288                   // padded slots per bucket (avg 8184, +50%)
#define NBIN_BLOCKS 200

typedef unsigned int uint32;
typedef unsigned short ushort;
typedef unsigned char uchar;
using short8 = __attribute__((ext_vector_type(8))) short;
using f32x4  = __attribute__((ext_vector_type(4))) float;

__device__ inline float bf_lo(uint32 u) { return __uint_as_float(u << 16); }
__device__ inline float bf_hi(uint32 u) { return __uint_as_float(u & 0xFFFF0000u); }
__device__ inline uint32 f2bf(float f) {
    uint32 u = __float_as_uint(f);
    return (u + 0x7FFFu + ((u >> 16) & 1u)) >> 16;  // RNE
}
__device__ inline uint32 pack2bf(float a, float b) { return f2bf(a) | (f2bf(b) << 16); }

// fp8 e4m3 (OCP) helpers — HW cvt on gfx950
__device__ inline uchar f32_to_fp8(float f) {
    __hip_fp8_e4m3 v(f);
    return (uchar)v.__x;
}
__device__ inline float2 fp8x2_to_f32(ushort u) {
    __hip_fp8x2_e4m3 v;
    v.__x = (__hip_fp8x2_storage_t)u;
    return (float2)v;
}

// ---------------- wt_init: W1T + W2T bf16 transposes + gcursor init ----------------

__global__ __launch_bounds__(256) void wt_init_kernel(const float* __restrict__ W1,
                                                      const float* __restrict__ W2,
                                                      ushort* __restrict__ w1t,
                                                      ushort* __restrict__ w2t,
                                                      int* __restrict__ gcursor) {
    int id = blockIdx.x * blockDim.x + threadIdx.x;
    if (id < IND * HID) {
        int n = id & 63, k = id >> 6;
        w1t[(size_t)n * IND + k] = (ushort)f2bf(W1[(size_t)k * HID + n]);
    } else if (id < IND * HID + 48 * HID) {
        int id2 = id - IND * HID;
        int n = id2 >> 6, k = id2 & 63;
        w2t[id2] = (n < NC) ? (ushort)f2bf(W2[(size_t)k * NC + n]) : (ushort)0;
    }
    if (id < NBKT) gcursor[id] = id * CAP;
}

// ---------------- bin: bucket edges into padded staging ----------------

__global__ __launch_bounds__(512) void bin_kernel(const int* __restrict__ src,
                                                  const int* __restrict__ dst,
                                                  int* __restrict__ gcursor,
                                                  int* __restrict__ packed, int E) {
    __shared__ int hist[NBKT], base[NBKT], cur[NBKT];
    int b = blockIdx.x, t = threadIdx.x;
    int epb = (E + gridDim.x - 1) / gridDim.x;
    int lo = b * epb;
    int hi = lo + epb; if (hi > E) hi = E;
    for (int i = t; i < NBKT; i += 512) { hist[i] = 0; cur[i] = 0; }
    __syncthreads();
    for (int e = lo + t; e < hi; e += 512) atomicAdd(&hist[dst[e] >> 8], 1);
    __syncthreads();
    for (int i = t; i < NBKT; i += 512)
        if (hist[i]) base[i] = atomicAdd(&gcursor[i], hist[i]);
    __syncthreads();
    for (int e = lo + t; e < hi; e += 512) {
        int d = dst[e], s = src[e];
        int bk = d >> 8;
        int pos = base[bk] + atomicAdd(&cur[bk], 1);
        packed[pos] = ((d & 255) << 17) | s;
    }
}

// ---------------- csr_bucket: per-bucket node sort -> padded CSR + dinv ----------------

__global__ __launch_bounds__(256) void csr_bucket_kernel(const int* __restrict__ packed,
                                                         const int* __restrict__ gcursor,
                                                         int* __restrict__ rowptr,
                                                         int* __restrict__ rowend,
                                                         int* __restrict__ colx,
                                                         float* __restrict__ dinv) {
    __shared__ int hist[BWN], pfx[BWN], cur[BWN];
    int b = blockIdx.x, t = threadIdx.x;
    int nlo = b * BWN;
    int ncnt = NN - nlo; if (ncnt > BWN) ncnt = BWN;
    int ebeg = b * CAP, eend = gcursor[b];
    hist[t] = 0;
    __syncthreads();
    for (int e = ebeg + t; e < eend; e += 256) atomicAdd(&hist[packed[e] >> 17], 1);
    __syncthreads();
    int h = hist[t];
    pfx[t] = h;
    __syncthreads();
    for (int off = 1; off < 256; off <<= 1) {
        int u = (t >= off) ? pfx[t - off] : 0;
        __syncthreads();
        pfx[t] += u;
        __syncthreads();
    }
    int excl = pfx[t] - h;
    cur[t] = excl;
    int g = nlo + t;
    if (t < ncnt) {
        rowptr[g] = ebeg + excl;
        rowend[g] = ebeg + excl + h;
        dinv[g] = rsqrtf((float)(h + 1));  // +1 self-loop
    }
    __syncthreads();
    for (int e = ebeg + t; e < eend; e += 256) {
        int p = packed[e];
        int dl = p >> 17;
        int s = p & 0x1FFFF;
        int pos = ebeg + atomicAdd(&cur[dl], 1);
        colx[pos] = s;
    }
}

// ---------------- Layer 1 GEMM (MFMA bf16, LDS-staged, reg-prefetch) ----------------
// NOTE: LDS staging beats LDS-free here (R12: 325 vs 290 µs total) — direct
// fragment loads stride 2KB across lanes, while staging keeps the x read fully
// coalesced and prefetch hides it under MFMA. Epilogue now emits fp8 e4m3.

__global__ __launch_bounds__(256) void gemm1_mfma(const float* __restrict__ x,
                                                  const ushort* __restrict__ w1t,
                                                  const float* __restrict__ dinv,
                                                  uchar* __restrict__ hs, int M) {
    __shared__ ushort As[64 * 64];
    __shared__ ushort Bs[64 * 64];
    char* Ab = (char*)As;
    char* Bb = (char*)Bs;

    int t = threadIdx.x;
    int row0 = blockIdx.x * 64;

    int srow = t >> 2;
    int klane = t & 3;
    int grow = row0 + srow; if (grow > M - 1) grow = M - 1;
    const float* xrow = x + (size_t)grow * IND;
    const char* wrow = (const char*)(w1t + (size_t)srow * IND);
    int swrow = srow * 128;
    int swx = (srow & 7) << 4;

    int l = t & 63;
    int w = t >> 6;
    int lr = l & 15;
    int lk = (l >> 4) * 16;
    int arow_b = (w * 16 + lr) * 128;
    int aswz = ((w * 16 + lr) & 7) << 4;

    f32x4 acc[4] = {};

    float4 rx[4]; uint2 rw[4];
#pragma unroll
    for (int i = 0; i < 4; ++i) {
        rx[i] = *(const float4*)(xrow + i * 16 + klane * 4);
        rw[i] = *(const uint2*)(wrow + i * 32 + klane * 8);
    }

    for (int k0 = 0; k0 < IND; k0 += 64) {
#pragma unroll
        for (int i = 0; i < 4; ++i) {
            int kb = i * 32 + klane * 8;
            uint2 pkd;
            pkd.x = pack2bf(rx[i].x, rx[i].y);
            pkd.y = pack2bf(rx[i].z, rx[i].w);
            *(uint2*)(Ab + swrow + (kb ^ swx)) = pkd;
            *(uint2*)(Bb + swrow + (kb ^ swx)) = rw[i];
        }
        __syncthreads();

        if (k0 + 64 < IND) {
#pragma unroll
            for (int i = 0; i < 4; ++i) {
                rx[i] = *(const float4*)(xrow + k0 + 64 + i * 16 + klane * 4);
                rw[i] = *(const uint2*)(wrow + (k0 + 64) * 2 + i * 32 + klane * 8);
            }
        }

        short8 a0 = *(const short8*)(Ab + arow_b + ((0 + lk) ^ aswz));
        short8 a1 = *(const short8*)(Ab + arow_b + ((64 + lk) ^ aswz));
#pragma unroll
        for (int ns = 0; ns < 4; ++ns) {
            int brow = ns * 16 + lr;
            int bswz = (brow & 7) << 4;
            short8 b0 = *(const short8*)(Bb + brow * 128 + ((0 + lk) ^ bswz));
            short8 b1 = *(const short8*)(Bb + brow * 128 + ((64 + lk) ^ bswz));
            acc[ns] = __builtin_amdgcn_mfma_f32_16x16x32_bf16(a0, b0, acc[ns], 0, 0, 0);
            acc[ns] = __builtin_amdgcn_mfma_f32_16x16x32_bf16(a1, b1, acc[ns], 0, 0, 0);
        }
        __syncthreads();
    }

    int rbase = row0 + w * 16 + (l >> 4) * 4;
    float dv[4];
#pragma unroll
    for (int j = 0; j < 4; ++j) dv[j] = (rbase + j < M) ? dinv[rbase + j] : 0.f;
#pragma unroll
    for (int ns = 0; ns < 4; ++ns) {
        int col = ns * 16 + lr;
#pragma unroll
        for (int j = 0; j < 4; ++j) {
            int row = rbase + j;
            if (row < M) hs[(size_t)row * HID + col] = f32_to_fp8(acc[ns][j] * dv[j]);
        }
    }
}

// ---------------- agg1: half-wave per node, fp8 gather (64B/row), bf16 h1 out ----------------

__global__ __launch_bounds__(256) void agg1_kernel(const ushort* __restrict__ hs,
                                                   const int* __restrict__ rowptr,
                                                   const int* __restrict__ rowend,
                                                   const int* __restrict__ colx,
                                                   const float* __restrict__ dinv,
                                                   const float* __restrict__ b1,
                                                   uint32* __restrict__ h1) {
    int node = (blockIdx.x * blockDim.x + threadIdx.x) >> 5;
    int l = threadIdx.x & 31;
    if (node >= NN) return;
    int beg = rowptr[node], end = rowend[node];
    float2 sf = fp8x2_to_f32(hs[(size_t)node * 32 + l]);  // self (dinv-scaled)
    float a0 = sf.x, a1 = sf.y;
    int e = beg;
    int n8 = beg + ((end - beg) & ~7);
    for (; e < n8; e += 8) {
        int c[8];
#pragma unroll
        for (int j = 0; j < 8; ++j) c[j] = __builtin_nontemporal_load(&colx[e + j]);
        ushort uu[8];
#pragma unroll
        for (int j = 0; j < 8; ++j) uu[j] = hs[(size_t)c[j] * 32 + l];
#pragma unroll
        for (int j = 0; j < 8; ++j) {
            float2 f = fp8x2_to_f32(uu[j]);
            a0 += f.x; a1 += f.y;
        }
    }
    for (; e < end; ++e) {
        float2 f = fp8x2_to_f32(hs[(size_t)__builtin_nontemporal_load(&colx[e]) * 32 + l]);
        a0 += f.x; a1 += f.y;
    }
    float d = dinv[node];
    float2 bb = *(const float2*)(b1 + 2 * l);
    float v0 = a0 * d + bb.x;
    float v1 = a1 * d + bb.y;
    v0 = v0 > 0.f ? v0 : 0.f;
    v1 = v1 > 0.f ? v1 : 0.f;
    __builtin_nontemporal_store(pack2bf(v0, v1), &h1[(size_t)node * 32 + l]);
}

// ---------------- Layer 2 GEMM (MFMA, LDS-free): h2b = bf16((h1 @ W2) * dinv) ----------------

__global__ __launch_bounds__(256) void gemm2_mfma(const ushort* __restrict__ h1,
                                                  const ushort* __restrict__ w2t,
                                                  const float* __restrict__ dinv,
                                                  ushort* __restrict__ h2b, int M) {
    int t = threadIdx.x;
    int w = t >> 6, l = t & 63;
    int lr = l & 15, lh = l >> 4;
    int row0 = blockIdx.x * 64 + w * 16;
    int arow = row0 + lr; if (arow > M - 1) arow = M - 1;
    const ushort* hrow = h1 + (size_t)arow * HID;

    f32x4 acc[3] = {};
#pragma unroll
    for (int ks = 0; ks < 2; ++ks) {
        short8 a = *(const short8*)(hrow + ks * 32 + lh * 8);
#pragma unroll
        for (int ns = 0; ns < 3; ++ns) {
            short8 b = *(const short8*)(w2t + (size_t)(ns * 16 + lr) * HID + ks * 32 + lh * 8);
            acc[ns] = __builtin_amdgcn_mfma_f32_16x16x32_bf16(a, b, acc[ns], 0, 0, 0);
        }
    }

    int rbase = row0 + lh * 4;
    float dv[4];
#pragma unroll
    for (int j = 0; j < 4; ++j) dv[j] = (rbase + j < M) ? dinv[rbase + j] : 0.f;
#pragma unroll
    for (int ns = 0; ns < 3; ++ns) {
        int col = ns * 16 + lr;
        if (col < NC) {
#pragma unroll
            for (int j = 0; j < 4; ++j) {
                int row = rbase + j;
                if (row < M) h2b[(size_t)row * NC + col] = (ushort)f2bf(acc[ns][j] * dv[j]);
            }
        }
    }
}

// ---------------- agg2 + bias + log_softmax: half-wave per node ----------------

__global__ __launch_bounds__(256) void agg2_kernel(const uint32* __restrict__ h2b,
                                                   const int* __restrict__ rowptr,
                                                   const int* __restrict__ rowend,
                                                   const int* __restrict__ colx,
                                                   const float* __restrict__ dinv,
                                                   const float* __restrict__ b2,
                                                   float* __restrict__ out) {
    int node = (blockIdx.x * blockDim.x + threadIdx.x) >> 5;
    int l = threadIdx.x & 31;
    if (node >= NN) return;
    bool act = l < 20;
    int beg = rowptr[node], end = rowend[node];
    float a0 = 0.f, a1 = 0.f;
    if (act) {
        uint32 u = h2b[(size_t)node * 20 + l];
        a0 = bf_lo(u); a1 = bf_hi(u);
    }
    int e = beg;
    int n8 = beg + ((end - beg) & ~7);
    for (; e < n8; e += 8) {
        int c[8];
#pragma unroll
        for (int j = 0; j < 8; ++j) c[j] = __builtin_nontemporal_load(&colx[e + j]);
        if (act) {
            uint32 uu[8];
#pragma unroll
            for (int j = 0; j < 8; ++j) uu[j] = h2b[(size_t)c[j] * 20 + l];
#pragma unroll
            for (int j = 0; j < 8; ++j) { a0 += bf_lo(uu[j]); a1 += bf_hi(uu[j]); }
        }
    }
    for (; e < end; ++e) {
        int c = __builtin_nontemporal_load(&colx[e]);
        if (act) {
            uint32 ue = h2b[(size_t)c * 20 + l];
            a0 += bf_lo(ue); a1 += bf_hi(ue);
        }
    }

    float d = dinv[node];
    float v0 = -INFINITY, v1 = -INFINITY;
    if (act) {
        float2 bb = *(const float2*)(b2 + 2 * l);
        v0 = a0 * d + bb.x;
        v1 = a1 * d + bb.y;
    }
    float m = fmaxf(v0, v1);
#pragma unroll
    for (int off = 16; off; off >>= 1) m = fmaxf(m, __shfl_xor(m, off));
    float s = act ? (expf(v0 - m) + expf(v1 - m)) : 0.f;
#pragma unroll
    for (int off = 16; off; off >>= 1) s += __shfl_xor(s, off);
    if (act) {
        float ls = logf(s);
        __builtin_nontemporal_store(v0 - m - ls, &out[(size_t)node * NC + 2 * l]);
        __builtin_nontemporal_store(v1 - m - ls, &out[(size_t)node * NC + 2 * l + 1]);
    }
}

// ---------------- launch ----------------

extern "C" void kernel_launch(void* const* d_in, const int* in_sizes, int n_in,
                              void* d_out, int out_size, void* d_ws, size_t ws_size,
                              hipStream_t stream) {
    const float* x  = (const float*)d_in[0];
    const int* ei   = (const int*)d_in[1];
    const float* W1 = (const float*)d_in[2];
    const float* b1 = (const float*)d_in[3];
    const float* W2 = (const float*)d_in[4];
    const float* b2 = (const float*)d_in[5];
    float* out = (float*)d_out;

    const int E = in_sizes[1] / 2;
    const int* src = ei;
    const int* dst = ei + E;

    char* p = (char*)d_ws;
    size_t off = 0;
    auto carve = [&](size_t bytes) {
        void* q = p + off;
        off = (off + bytes + 255) & ~(size_t)255;
        return q;
    };
    int* gcursor  = (int*)carve((size_t)NBKT * 4);
    int* rowptr   = (int*)carve((size_t)NN * 4);
    int* rowend   = (int*)carve((size_t)NN * 4);
    float* dinv   = (float*)carve((size_t)NN * 4);
    ushort* w1t   = (ushort*)carve((size_t)IND * HID * 2);      // bf16 W1^T [64][512]
    ushort* w2t   = (ushort*)carve((size_t)48 * HID * 2);       // bf16 W2^T [48][64], padded
    uchar* hs     = (uchar*)carve((size_t)NN * HID);            // fp8 e4m3 [NN][64]
    uint32* h1    = (uint32*)carve((size_t)NN * 32 * 4);        // bf16 pairs [NN][32]
    ushort* h2b   = (ushort*)carve((size_t)NN * NC * 2);        // bf16 [NN][40]
    int* colx     = (int*)carve((size_t)NBKT * CAP * 4);        // padded CSR cols
    int* packed   = (int*)carve((size_t)NBKT * CAP * 4);        // padded bin staging

    wt_init_kernel<<<(IND * HID + 48 * HID + 255) / 256, 256, 0, stream>>>(W1, W2, w1t, w2t, gcursor);
    bin_kernel<<<NBIN_BLOCKS, 512, 0, stream>>>(src, dst, gcursor, packed, E);
    csr_bucket_kernel<<<NBKT, 256, 0, stream>>>(packed, gcursor, rowptr, rowend, colx, dinv);
    gemm1_mfma<<<(NN + 63) / 64, 256, 0, stream>>>(x, w1t, dinv, hs, NN);
    agg1_kernel<<<(NN * 32 + 255) / 256, 256, 0, stream>>>((const ushort*)hs, rowptr, rowend, colx, dinv, b1, h1);
    gemm2_mfma<<<(NN + 63) / 64, 256, 0, stream>>>((const ushort*)h1, w2t, dinv, h2b, NN);
    agg2_kernel<<<(NN * 32 + 255) / 256, 256, 0, stream>>>((const uint32*)h2b, rowptr, rowend, colx, dinv, b2, out);
}